// Round 10
// baseline (102.941 us; speedup 1.0000x reference)
//
#include <hip/hip_runtime.h>

// QuantGelu: y = pre_x_int * sigmoid_int * (scaler/128)
//   pre_x_int = clip(round(x/scaler), -128, 127)  [per-channel scaler, D=4096]
//   sigmoid via integer shift-exp over {x_int, -row_max}
//
// Round-10: occupancy experiment. BLK=256 (4 waves/block), CPT=16, RPB=4,
// grid=2048 -> 8 co-resident blocks/CU (vs 4 with 8-wave blocks) so
// independent blocks fill each other's barrier/div-latency gaps.
// Register diet to keep VGPR<=64 WITHOUT a forced launch bound (r6 lesson):
// pre packed as i8 bytes, slots as bytes, only rs_ kept in regs; s reloaded
// from the L1/L2-hot scaler array per phase. Element math identical to
// rounds 5-9 -> bit-same output.

#define D 4096
#define BLK 256
#define CPT 16          // BLK*CPT == D
#define RPB 4
#define NW (BLK / 64)   // 4
#define NSLOT 9         // x0 slots covered by fast path (data span <= 8)
#define TENT (NSLOT * 256)
#define EPS 1e-4f
#define F2_31 2147483648.0f   // fl32(2^31 - 1)

typedef float f32x4 __attribute__((ext_vector_type(4)));

// Exact floor(fl(xi/x0)) for integer-valued xi, integer x0 in [-64,-1],
// clamped ratio in [0,15]: divisible case error << EPS; non-divisible case
// distance to integer >= 1/|x0| >= 1/64 >> EPS. ldexpf = v_ldexp_f32; q<0
// (em path) -> inf, matching np.exp2(15-q)=inf, absorbed by min(esum,2^31).
__device__ __forceinline__ float exp_fast(float xi, float nx0, float rx0) {
    const float q = floorf(fmaf(xi, rx0, EPS));
    const float r = fmaf(nx0, q, xi);      // xi - x0*q, exact (small ints)
    const float e = fmaf(r, 0.5f, nx0);    // r/2 - x0, halves, exact
    return floorf(ldexpf(e, 15 - (int)q)); // e > 0 -> max(.,0) redundant
}

// Fully-IEEE path, exact for any x0 (block-uniform fallback only).
__device__ __forceinline__ float exp_slow(float xi, float x0) {
    xi = fmaxf(xi, 15.0f * x0);
    const float q = floorf(xi / x0);
    const float r = fmaf(-x0, q, xi);
    const float e = fmaf(r, 0.5f, -x0);
    return fmaxf(floorf(e * ldexpf(1.0f, 15 - (int)q)), 0.0f);
}

__global__ __launch_bounds__(BLK) void quantgelu_kernel(
    const float* __restrict__ x, const float* __restrict__ scaler,
    float* __restrict__ out, int nrows)
{
    const int tid  = threadIdx.x;
    const int wid  = tid >> 6;
    const int lane = tid & 63;
    const int row0 = blockIdx.x * RPB;

    __shared__ float eit[TENT];
    __shared__ float sigt[TENT];
    __shared__ __align__(16) float smax2[2][NW];

    // thread t owns columns k*1024 + t*4 + j, k=0..3, j=0..3

    // ---- prefetch row 0 ASAP ----
    float4 xv[4];
    if (row0 < nrows) {
        const long long b0 = (long long)row0 * D;
        #pragma unroll
        for (int k = 0; k < 4; ++k)
            xv[k] = *reinterpret_cast<const float4*>(x + b0 + k * 1024 + tid * 4);
    }

    // ---- per-channel rs + x0 range (s NOT kept in regs; reloaded later) ----
    float rs_[CPT];
    float x0mn, x0mx;
    {
        float mn = 1.0f, mx = -1e30f;
        #pragma unroll
        for (int k = 0; k < 4; ++k) {
            const float4 sv = *reinterpret_cast<const float4*>(scaler + k * 1024 + tid * 4);
            const float ss[4] = {sv.x, sv.y, sv.z, sv.w};
            #pragma unroll
            for (int j = 0; j < 4; ++j) {
                const float s = ss[j];
                rs_[k * 4 + j] = 1.0f / s;                  // Markstein seed
                const float x0 = floorf(-1.0f / (s * 1.702f));  // IEEE div
                mn = fminf(mn, x0);
                mx = fmaxf(mx, x0);
            }
        }
        #pragma unroll
        for (int off = 1; off < 64; off <<= 1) {
            mn = fminf(mn, __shfl_xor(mn, off));
            mx = fmaxf(mx, __shfl_xor(mx, off));
        }
        if (lane == 0) { smax2[0][wid] = mn; smax2[1][wid] = mx; }
        __syncthreads();
        x0mn = mn; x0mx = mx;
        #pragma unroll
        for (int w = 0; w < NW; ++w) {
            x0mn = fminf(x0mn, smax2[0][w]);
            x0mx = fmaxf(x0mx, smax2[1][w]);
        }
        __syncthreads();    // smax2 free for row-max reuse
    }

    const int  nslots = (int)(x0mx - x0mn) + 1;
    const bool ok = (x0mn >= -64.0f) && (nslots <= NSLOT);   // block-uniform
    const int  nent = nslots << 8;              // multiple of 256

    // slot bytes (recompute x0 from reloaded s; 16 divs, setup-only)
    unsigned slotpk[4];
    #pragma unroll
    for (int k = 0; k < 4; ++k) {
        const float4 sv = *reinterpret_cast<const float4*>(scaler + k * 1024 + tid * 4);
        const float ss[4] = {sv.x, sv.y, sv.z, sv.w};
        unsigned b = 0u;
        #pragma unroll
        for (int j = 0; j < 4; ++j) {
            const float x0 = floorf(-1.0f / (ss[j] * 1.702f));
            const float sl = fminf(fmaxf(x0 - x0mn, 0.0f), 255.0f);
            b |= ((unsigned)(int)sl & 0xffu) << (8 * j);
        }
        slotpk[k] = b;
    }

    // lane-slot constants: lane l serves slot l
    const float x0l  = x0mn + (float)lane;
    const float nx0l = -x0l;
    const float rx0l = 1.0f / x0l;              // IEEE div, 1x per block
    const float c15l = 15.0f * x0l;

    // block-invariant ei table: ei(slot, d) = int_exp_shift(-d, x0_slot)
    if (ok) {
        for (int e = tid; e < nent; e += BLK) {
            const int   slot = e >> 8;          // wave-uniform (64 | 256)
            const float x0v  = x0mn + (float)slot;
            float xi = -(float)(e & 255);
            xi = xi + floorf(xi * 0.5f) - floorf(xi * 0.0625f);
            xi = fmaxf(xi, 15.0f * x0v);
            eit[e] = exp_fast(xi, -x0v, __shfl(rx0l, slot));
        }
    }
    // eit writes ordered before first build's reads by barrier A below.

    for (int r = 0; r < RPB; ++r) {
        const int row = row0 + r;
        if (row >= nrows) break;                // block-uniform
        const long long rb = (long long)row * D;

        // phase 1: quantize (Markstein correctly-rounded div) + row max,
        // pre packed as i8 bytes; s reloaded (L1/L2-hot, 16 KB array)
        float vmax = -INFINITY;
        unsigned pk[4];
        #pragma unroll
        for (int k = 0; k < 4; ++k) {
            const float4 sv = *reinterpret_cast<const float4*>(scaler + k * 1024 + tid * 4);
            const float ss[4] = {sv.x, sv.y, sv.z, sv.w};
            const float* xa = reinterpret_cast<const float*>(&xv[k]);
            unsigned b = 0u;
            #pragma unroll
            for (int j = 0; j < 4; ++j) {
                const int i = k * 4 + j;
                const float q0 = xa[j] * rs_[i];
                const float rr = fmaf(-ss[j], q0, xa[j]);
                const float p  = __builtin_amdgcn_fmed3f(
                                    rintf(fmaf(rr, rs_[i], q0)), -128.0f, 127.0f);
                vmax = fmaxf(vmax, p);
                b |= ((unsigned)(int)p & 0xffu) << (8 * j);
            }
            pk[k] = b;
        }

        // prefetch next row into freed xv (flies across reduce+build)
        if (r + 1 < RPB && row + 1 < nrows) {
            #pragma unroll
            for (int k = 0; k < 4; ++k)
                xv[k] = *reinterpret_cast<const float4*>(x + rb + D + k * 1024 + tid * 4);
        }

        // 64-lane butterfly max + cross-wave
        #pragma unroll
        for (int off = 1; off < 64; off <<= 1)
            vmax = fmaxf(vmax, __shfl_xor(vmax, off));
        if (lane == 0) smax2[0][wid] = vmax;
        __syncthreads();                        // A
        {
            const float4 a = *reinterpret_cast<const float4*>(&smax2[0][0]);
            vmax = fmaxf(fmaxf(a.x, a.y), fmaxf(a.z, a.w));
        }

        const float xm  = -vmax;
        const float xmt = xm + floorf(xm * 0.5f) - floorf(xm * 0.0625f);
        const int   vmi = (int)vmax;

        // phase 2: per-row sig table (scaler/128's 2^-7 folded in)
        if (ok) {
            const float em_l = exp_fast(fmaxf(xmt, c15l), nx0l, rx0l);
            for (int e = tid; e < nent; e += BLK) {
                const int   slot = e >> 8;      // wave-uniform
                const float ei   = eit[e];
                const float em   = __shfl(em_l, slot);
                const float f    = floorf(F2_31 / fminf(ei + em, F2_31)); // IEEE div
                sigt[e] = floorf((ei * f) * 0x1p-24f) * 0.0078125f;
            }
        }
        __syncthreads();                        // B (sigt ready)

        // phase 3: lookup + NT store (s reloaded)
        if (ok) {
            #pragma unroll
            for (int k = 0; k < 4; ++k) {
                const float4 sv = *reinterpret_cast<const float4*>(scaler + k * 1024 + tid * 4);
                const float ss[4] = {sv.x, sv.y, sv.z, sv.w};
                f32x4 ov;
                #pragma unroll
                for (int j = 0; j < 4; ++j) {
                    const int pi = (int)(signed char)((pk[k] >> (8 * j)) & 0xffu);
                    const int sl = (int)((slotpk[k] >> (8 * j)) & 0xffu);
                    ov[j] = ((float)pi * sigt[(sl << 8) + (vmi - pi)]) * ss[j];
                }
                __builtin_nontemporal_store(
                    ov, reinterpret_cast<f32x4*>(out + rb + k * 1024 + tid * 4));
            }
        } else {
            // rare block-uniform exact fallback (x0 out of table window)
            #pragma unroll
            for (int k = 0; k < 4; ++k) {
                const float4 sv = *reinterpret_cast<const float4*>(scaler + k * 1024 + tid * 4);
                const float ss[4] = {sv.x, sv.y, sv.z, sv.w};
                f32x4 ov;
                #pragma unroll
                for (int j = 0; j < 4; ++j) {
                    const float x0 = floorf(-1.0f / (ss[j] * 1.702f));
                    const float pf = (float)(int)(signed char)((pk[k] >> (8 * j)) & 0xffu);
                    float xi = pf - vmax;
                    xi = xi + floorf(xi * 0.5f) - floorf(xi * 0.0625f);
                    const float ei = exp_slow(xi, x0);
                    const float em = exp_slow(xmt, x0);
                    const float factor = floorf(F2_31 / fminf(ei + em, F2_31));
                    ov[j] = (pf * floorf((ei * factor) * 0x1p-24f))
                            * (ss[j] * 0.0078125f);
                }
                __builtin_nontemporal_store(
                    ov, reinterpret_cast<f32x4*>(out + rb + k * 1024 + tid * 4));
            }
        }
    }
}

extern "C" void kernel_launch(void* const* d_in, const int* in_sizes, int n_in,
                              void* d_out, int out_size, void* d_ws, size_t ws_size,
                              hipStream_t stream) {
    const float* x      = (const float*)d_in[0];
    const float* scaler = (const float*)d_in[1];
    float* out          = (float*)d_out;

    const int nrows = in_sizes[0] / D;                 // 8192
    const int grid  = (nrows + RPB - 1) / RPB;         // 2048
    quantgelu_kernel<<<grid, BLK, 0, stream>>>(x, scaler, out, nrows);
}

// Round 11
// 48.658 us; speedup vs baseline: 2.1156x; 2.1156x over previous
//
#include <hip/hip_runtime.h>

// QuantGelu: y = pre_x_int * sigmoid_int * (scaler/128)
//   pre_x_int = clip(round(x/scaler), -128, 127)  [per-channel scaler, D=4096]
//   sigmoid via integer shift-exp over {x_int, -row_max}
//
// FINAL (round-5 structure, best of rounds 0-10 at 48.8 us):
//   - one block per 8 rows, BLK=512, CPT=8
//   - per-block LDS ei table (block-invariant), per-row LDS sig table:
//     sigmoid_int is a function of (d = row_max - pre, x0) only
//   - Markstein correctly-rounded division for quantize (bit-exact vs IEEE)
//   - em hoisted per-lane-slot + __shfl broadcast
//   - non-temporal float4 output stores
// Structural variants tried and rejected: row-pair barrier grouping (r7),
// 1-barrier software pipeline (r8), 2-barrier phase separation (r9),
// 4-wave small blocks (r10) -- all >= 49.4 us. Forced min-occupancy launch
// bound spills to scratch (r6: 32 VGPR, +250 MB traffic, 112 us).

#define D 4096
#define BLK 512
#define CPT 8           // BLK*CPT == D
#define RPB 8
#define NW (BLK / 64)
#define NSLOT 16        // x0 slots covered by fast path
#define TENT (NSLOT * 256)
#define EPS 1e-4f
#define F2_31 2147483648.0f   // fl32(2^31 - 1)

typedef float f32x4 __attribute__((ext_vector_type(4)));

// Exact floor(fl(xi/x0)) for integer-valued xi, integer x0 in [-64,-1],
// clamped ratio in [0,15]: divisible case error << EPS; non-divisible case
// distance to integer >= 1/|x0| >= 1/64 >> EPS. ldexpf = v_ldexp_f32; q<0
// (em path) -> inf, matching np.exp2(15-q)=inf, absorbed by min(esum,2^31).
__device__ __forceinline__ float exp_fast(float xi, float nx0, float rx0) {
    const float q = floorf(fmaf(xi, rx0, EPS));
    const float r = fmaf(nx0, q, xi);      // xi - x0*q, exact (small ints)
    const float e = fmaf(r, 0.5f, nx0);    // r/2 - x0, halves, exact
    return floorf(ldexpf(e, 15 - (int)q)); // e > 0 -> max(.,0) redundant
}

// Fully-IEEE path, exact for any x0 (fallback only).
__device__ __forceinline__ float exp_slow(float xi, float x0) {
    xi = fmaxf(xi, 15.0f * x0);
    const float q = floorf(xi / x0);
    const float r = fmaf(-x0, q, xi);
    const float e = fmaf(r, 0.5f, -x0);
    return fmaxf(floorf(e * ldexpf(1.0f, 15 - (int)q)), 0.0f);
}

__global__ __launch_bounds__(BLK) void quantgelu_kernel(
    const float* __restrict__ x, const float* __restrict__ scaler,
    float* __restrict__ out, int nrows)
{
    const int tid  = threadIdx.x;
    const int wid  = tid >> 6;
    const int lane = tid & 63;
    const int row0 = blockIdx.x * RPB;

    __shared__ __align__(16) float sred[2][NW];
    __shared__ __align__(16) float smax[NW];
    __shared__ float eit[TENT];
    __shared__ float sigt[TENT];

    // ---- per-channel constants (hoisted across RPB rows) ----
    float s_[CPT], rs_[CPT], s128_[CPT], x0_[CPT];
    #pragma unroll
    for (int k = 0; k < CPT / 4; ++k) {
        const int col = k * (BLK * 4) + tid * 4;
        const float4 sv = *reinterpret_cast<const float4*>(scaler + col);
        const float ss[4] = {sv.x, sv.y, sv.z, sv.w};
        #pragma unroll
        for (int j = 0; j < 4; ++j) {
            const int i = k * 4 + j;
            const float s = ss[j];
            s_[i]    = s;
            rs_[i]   = 1.0f / s;               // RN(1/s): Markstein seed
            s128_[i] = s * 0.0078125f;
            x0_[i]   = floorf(-1.0f / (s * 1.702f));   // IEEE div, 1x/8 rows
        }
    }

    // prefetch row 0 early
    long long base = (long long)row0 * D;
    float4 xv[CPT / 4];
    if (row0 < nrows) {
        #pragma unroll
        for (int k = 0; k < CPT / 4; ++k)
            xv[k] = *reinterpret_cast<const float4*>(x + base + k * (BLK * 4) + tid * 4);
    }

    // ---- block-wide x0 range ----
    float x0mn = x0_[0], x0mx = x0_[0];
    #pragma unroll
    for (int i = 1; i < CPT; ++i) {
        x0mn = fminf(x0mn, x0_[i]);
        x0mx = fmaxf(x0mx, x0_[i]);
    }
    #pragma unroll
    for (int off = 1; off < 64; off <<= 1) {
        x0mn = fminf(x0mn, __shfl_xor(x0mn, off));
        x0mx = fmaxf(x0mx, __shfl_xor(x0mx, off));
    }
    if ((tid & 63) == 0) { sred[0][wid] = x0mn; sred[1][wid] = x0mx; }
    __syncthreads();
    #pragma unroll
    for (int w = 0; w < NW; ++w) {
        x0mn = fminf(x0mn, sred[0][w]);
        x0mx = fmaxf(x0mx, sred[1][w]);
    }

    const int  nslots = (int)(x0mx - x0mn) + 1;
    const bool ok = (x0mn >= -64.0f) && (nslots <= NSLOT);   // block-uniform
    const int  nent = nslots << 8;              // multiple of 256

    int bo_[CPT];
    #pragma unroll
    for (int i = 0; i < CPT; ++i)
        bo_[i] = ((int)(x0_[i] - x0mn)) << 8;

    // lane-slot constants: lane l serves slot l (garbage for l >= nslots, unused)
    const float x0l  = x0mn + (float)lane;
    const float nx0l = -x0l;
    const float rx0l = 1.0f / x0l;              // IEEE div, 1x per block
    const float c15l = 15.0f * x0l;

    // block-invariant ei table: ei(slot, d) = int_exp_shift(-d, x0_slot)
    if (ok) {
        for (int e = tid; e < nent; e += BLK) {
            const int   slot = e >> 8;
            const float x0v  = x0mn + (float)slot;
            float xi = -(float)(e & 255);
            xi = xi + floorf(xi * 0.5f) - floorf(xi * 0.0625f);
            xi = fmaxf(xi, 15.0f * x0v);
            eit[e] = exp_fast(xi, -x0v, __shfl(rx0l, slot));
        }
    }
    // eit writes ordered before first build's reads by barrier A below.

    for (int r = 0; r < RPB; ++r) {
        const int row = row0 + r;
        if (row >= nrows) break;                // block-uniform

        // prefetch next row under this row's work
        float4 xn[CPT / 4];
        if (r + 1 < RPB && row + 1 < nrows) {
            #pragma unroll
            for (int k = 0; k < CPT / 4; ++k)
                xn[k] = *reinterpret_cast<const float4*>(x + base + D + k * (BLK * 4) + tid * 4);
        }

        // phase 1: quantize (Markstein correctly-rounded div) + row max
        float pre[CPT];
        float vmax = -INFINITY;
        const float* xf = reinterpret_cast<const float*>(xv);
        #pragma unroll
        for (int i = 0; i < CPT; ++i) {
            const float q0 = xf[i] * rs_[i];
            const float rr = fmaf(-s_[i], q0, xf[i]);
            const float qq = fmaf(rr, rs_[i], q0);   // = RN(x/s)
            float p = rintf(qq);
            p = fminf(fmaxf(p, -128.0f), 127.0f);
            pre[i] = p;
            vmax = fmaxf(vmax, p);
        }
        #pragma unroll
        for (int off = 1; off < 64; off <<= 1)
            vmax = fmaxf(vmax, __shfl_xor(vmax, off));
        if ((tid & 63) == 0) smax[wid] = vmax;
        __syncthreads();                        // A
        {
            const float4 a = *reinterpret_cast<const float4*>(smax);
            const float4 b = *reinterpret_cast<const float4*>(smax + 4);
            vmax = fmaxf(fmaxf(fmaxf(a.x, a.y), fmaxf(a.z, a.w)),
                         fmaxf(fmaxf(b.x, b.y), fmaxf(b.z, b.w)));
        }

        const float xm  = -vmax;
        const float xmt = xm + floorf(xm * 0.5f) - floorf(xm * 0.0625f);

        float res[CPT];
        if (ok) {
            // per-lane slot em, once per row (lanes >= nslots: unused garbage)
            const float em_l = exp_fast(fmaxf(xmt, c15l), nx0l, rx0l);

            // per-row sig table (nent wave-aligned -> whole waves at the shfl)
            for (int e = tid; e < nent; e += BLK) {
                const int   slot = e >> 8;
                const float em   = __shfl(em_l, slot);
                const float ei   = eit[e];
                const float esum   = fminf(ei + em, F2_31);
                const float factor = floorf(F2_31 / esum);    // IEEE div
                sigt[e] = floorf((ei * factor) * 0x1p-24f);
            }
            __syncthreads();                    // B (sigt ready)

            #pragma unroll
            for (int i = 0; i < CPT; ++i) {
                const int d = (int)(vmax - pre[i]);     // exact, [0,255]
                res[i] = (pre[i] * sigt[bo_[i] + d]) * s128_[i];
            }
        } else {
            // rare block-uniform exact fallback (x0 out of table range)
            #pragma unroll
            for (int i = 0; i < CPT; ++i) {
                const float x0 = x0_[i];
                float xi = pre[i] - vmax;
                xi = xi + floorf(xi * 0.5f) - floorf(xi * 0.0625f);
                const float ei = exp_slow(xi, x0);
                const float em = exp_slow(xmt, x0);
                const float esum   = fminf(ei + em, F2_31);
                const float factor = floorf(F2_31 / esum);
                const float sig    = floorf((ei * factor) * 0x1p-24f);
                res[i] = (pre[i] * sig) * s128_[i];
            }
        }

        // non-temporal stores: out is write-once; don't evict x from L2/L3
        #pragma unroll
        for (int k = 0; k < CPT / 4; ++k) {
            f32x4 ov;
            ov.x = res[k * 4 + 0]; ov.y = res[k * 4 + 1];
            ov.z = res[k * 4 + 2]; ov.w = res[k * 4 + 3];
            __builtin_nontemporal_store(
                ov, reinterpret_cast<f32x4*>(out + base + k * (BLK * 4) + tid * 4));
        }

        base += D;
        #pragma unroll
        for (int k = 0; k < CPT / 4; ++k) xv[k] = xn[k];
    }
}

extern "C" void kernel_launch(void* const* d_in, const int* in_sizes, int n_in,
                              void* d_out, int out_size, void* d_ws, size_t ws_size,
                              hipStream_t stream) {
    const float* x      = (const float*)d_in[0];
    const float* scaler = (const float*)d_in[1];
    float* out          = (float*)d_out;

    const int nrows = in_sizes[0] / D;                 // 8192
    const int grid  = (nrows + RPB - 1) / RPB;         // 1024
    quantgelu_kernel<<<grid, BLK, 0, stream>>>(x, scaler, out, nrows);
}